// Round 2
// baseline (2546.504 us; speedup 1.0000x reference)
//
#include <hip/hip_runtime.h>
#include <hip/hip_bf16.h>

#define NN 50000
#define NE 600000
#define IND 16
#define EDD 8
#define HIDD 128
#define NH 4
#define CC 32
#define EMBD 64
#define FEATD 64

typedef __hip_bfloat16 bf16;

__device__ __forceinline__ float b2f(bf16 v) { return __bfloat162float(v); }

// Load input element i from a buffer whose dtype is decided at runtime.
template <bool F32>
__device__ __forceinline__ float LD(const void* p, long long i) {
    if constexpr (F32) return ((const float*)p)[i];
    else return __bfloat162float(((const bf16*)p)[i]);
}

// ---- dtype detector: bf16 normal data has no 0x7F80-exponent patterns;
// fp32 data misread as bf16 has ~0.4% of half-words with exp==0xFF.
__global__ void k_detect(const unsigned short* __restrict__ x, int nelem, int* __restrict__ flag) {
    __shared__ int cnt;
    if (threadIdx.x == 0) cnt = 0;
    __syncthreads();
    int c = 0;
    for (int i = threadIdx.x; i < nelem; i += blockDim.x) {
        if ((x[i] & 0x7F80u) == 0x7F80u) c++;
    }
    atomicAdd(&cnt, c);
    __syncthreads();
    if (threadIdx.x == 0) *flag = (cnt > 8) ? 1 : 0;  // 1 => inputs are fp32
}

// ---- z[n] = concat(relu(x[n] @ W_in + b_in), emb[node_idx[n]])
template <bool F32>
__device__ void build_z_impl(const void* x, const int* __restrict__ node_idx, const void* emb,
                             const void* W_in, const void* b_in, float* __restrict__ z) {
    int n = blockIdx.x, t = threadIdx.x;  // 128
    if (t < FEATD) {
        float acc = LD<F32>(b_in, t);
        #pragma unroll
        for (int k = 0; k < IND; k++)
            acc += LD<F32>(x, (long long)n * IND + k) * LD<F32>(W_in, k * FEATD + t);
        z[n * HIDD + t] = fmaxf(acc, 0.f);
    } else {
        int j = t - FEATD;
        z[n * HIDD + t] = LD<F32>(emb, (long long)node_idx[n] * EMBD + j);
    }
}
__global__ void k_build_z(const int* flag, const void* x, const int* node_idx, const void* emb,
                          const void* W_in, const void* b_in, float* z) {
    if (*flag) build_z_impl<true>(x, node_idx, emb, W_in, b_in, z);
    else       build_z_impl<false>(x, node_idx, emb, W_in, b_in, z);
}

// ---- xl = z@Wl+bl ; xr = z@Wr+br, 4 nodes per block (weight reuse), bf16 outputs
template <bool F32>
__device__ void proj_impl(const float* __restrict__ z, const void* Wl, const void* bl,
                          const void* Wr, const void* br, bf16* __restrict__ xl,
                          bf16* __restrict__ xr) {
    __shared__ float zr[4][HIDD];
    int n0 = blockIdx.x * 4, t = threadIdx.x;  // 128
    #pragma unroll
    for (int j = 0; j < 4; j++) zr[j][t] = z[(n0 + j) * HIDD + t];
    __syncthreads();
    float al[4], ar[4];
    float blv = LD<F32>(bl, t), brv = LD<F32>(br, t);
    #pragma unroll
    for (int j = 0; j < 4; j++) { al[j] = blv; ar[j] = brv; }
    for (int k = 0; k < HIDD; k++) {
        float wl = LD<F32>(Wl, k * HIDD + t);
        float wr = LD<F32>(Wr, k * HIDD + t);
        #pragma unroll
        for (int j = 0; j < 4; j++) {
            al[j] += zr[j][k] * wl;
            ar[j] += zr[j][k] * wr;
        }
    }
    #pragma unroll
    for (int j = 0; j < 4; j++) {
        xl[(n0 + j) * HIDD + t] = __float2bfloat16(al[j]);
        xr[(n0 + j) * HIDD + t] = __float2bfloat16(ar[j]);
    }
}
__global__ void k_proj(const int* flag, const float* z, const void* Wl, const void* bl,
                       const void* Wr, const void* br, bf16* xl, bf16* xr) {
    if (*flag) proj_impl<true>(z, Wl, bl, Wr, br, xl, xr);
    else       proj_impl<false>(z, Wl, bl, Wr, br, xl, xr);
}

// ---- zero agg + den
__global__ void k_init(float* __restrict__ agg, float* __restrict__ den) {
    int i = blockIdx.x * blockDim.x + threadIdx.x;
    if (i < NN * HIDD) agg[i] = 0.f;
    if (i < NN * NH) den[i] = 0.f;
}

// ---- fused edge pass: logits -> exp -> unnormalized scatter + den.
// Max-shift dropped: alpha is shift-invariant and |logit| is small here (no overflow).
template <bool F32>
__device__ void edge_impl(const void* ea, const int* __restrict__ ei, const void* We,
                          const void* be, const void* att, const bf16* __restrict__ xl,
                          const bf16* __restrict__ xr, float* __restrict__ agg,
                          float* __restrict__ den) {
    __shared__ float sWe[EDD * HIDD];
    __shared__ float sbt[2 * HIDD];  // [0:128)=be, [128:256)=att
    __shared__ float sea[2][EDD];
    int tid = threadIdx.x;  // 256 = 2 edges x 128 channels
    for (int i = tid; i < EDD * HIDD; i += 256) sWe[i] = LD<F32>(We, i);
    if (tid < HIDD) sbt[tid] = LD<F32>(be, tid);
    else            sbt[tid] = LD<F32>(att, tid - HIDD);
    int el = tid >> 7;
    int t = tid & 127;
    int e = blockIdx.x * 2 + el;  // grid = NE/2 exactly, no bounds check
    if (t < EDD) sea[el][t] = LD<F32>(ea, (long long)e * EDD + t);
    __syncthreads();
    int src = ei[e], dst = ei[NE + e];
    float ee = sbt[t];
    #pragma unroll
    for (int d = 0; d < EDD; d++) ee += sea[el][d] * sWe[d * HIDD + t];
    float xlv = b2f(xl[(long long)src * HIDD + t]);
    float s = xlv + b2f(xr[(long long)dst * HIDD + t]) + ee;
    s = (s >= 0.f) ? s : 0.2f * s;
    float ls = s * sbt[HIDD + t];
    #pragma unroll
    for (int m = 16; m; m >>= 1) ls += __shfl_xor(ls, m, 32);  // head-group reduce
    float ex = __expf(ls);
    int h = t >> 5;
    if ((t & 31) == 0) atomicAdd(&den[dst * NH + h], ex);
    atomicAdd(&agg[(long long)dst * HIDD + t], xlv * ex);
}
__global__ void k_edge(const int* flag, const void* ea, const int* ei, const void* We,
                       const void* be, const void* att, const bf16* xl, const bf16* xr,
                       float* agg, float* den) {
    if (*flag) edge_impl<true>(ea, ei, We, be, att, xl, xr, agg, den);
    else       edge_impl<false>(ea, ei, We, be, att, xl, xr, agg, den);
}

// ---- h = relu(agg/den + bo); z = LN(z + h)*g + beta
template <bool F32>
__device__ void fin_impl(const float* __restrict__ agg, const float* __restrict__ den,
                         const void* bo, float* __restrict__ z, const void* g, const void* beta) {
    int n = blockIdx.x, t = threadIdx.x;  // 128
    int wave = t >> 6, lane = t & 63;
    float dn = den[n * NH + (t >> 5)];
    float a = agg[n * HIDD + t];
    float hv = (dn > 0.f) ? a / dn : 0.f;
    hv = fmaxf(hv + LD<F32>(bo, t), 0.f);
    float v = z[n * HIDD + t] + hv;
    __shared__ float part[2], part2[2];
    float s = v;
    #pragma unroll
    for (int o = 32; o; o >>= 1) s += __shfl_down(s, o);
    if (lane == 0) part[wave] = s;
    __syncthreads();
    float mu = (part[0] + part[1]) * (1.f / HIDD);
    float d = v - mu;
    float s2 = d * d;
    #pragma unroll
    for (int o = 32; o; o >>= 1) s2 += __shfl_down(s2, o);
    if (lane == 0) part2[wave] = s2;
    __syncthreads();
    float var = (part2[0] + part2[1]) * (1.f / HIDD);
    z[n * HIDD + t] = d * rsqrtf(var + 1e-5f) * LD<F32>(g, t) + LD<F32>(beta, t);
}
__global__ void k_fin(const int* flag, const float* agg, const float* den, const void* bo,
                      float* z, const void* g, const void* beta) {
    if (*flag) fin_impl<true>(agg, den, bo, z, g, beta);
    else       fin_impl<false>(agg, den, bo, z, g, beta);
}

// ---- out[n] = z[n] @ W_out + b_out (one wave per node); output dtype follows flag
template <bool F32>
__device__ void head_impl(const float* __restrict__ z, const void* Wo, const void* bo, void* out) {
    int n = blockIdx.x;
    int lane = threadIdx.x;  // 64
    float acc = z[n * HIDD + lane] * LD<F32>(Wo, lane) +
                z[n * HIDD + 64 + lane] * LD<F32>(Wo, 64 + lane);
    #pragma unroll
    for (int o = 32; o; o >>= 1) acc += __shfl_down(acc, o);
    if (lane == 0) {
        float r = acc + LD<F32>(bo, 0);
        if constexpr (F32) ((float*)out)[n] = r;
        else               ((bf16*)out)[n] = __float2bfloat16(r);
    }
}
__global__ void k_head(const int* flag, const float* z, const void* Wo, const void* bo, void* out) {
    if (*flag) head_impl<true>(z, Wo, bo, out);
    else       head_impl<false>(z, Wo, bo, out);
}

extern "C" void kernel_launch(void* const* d_in, const int* in_sizes, int n_in,
                              void* d_out, int out_size, void* d_ws, size_t ws_size,
                              hipStream_t stream) {
    const void* x        = d_in[0];
    const int*  node_idx = (const int*)d_in[1];
    const int*  ei       = (const int*)d_in[2];
    const void* ea       = d_in[3];
    const void* emb      = d_in[4];
    const void* W_in     = d_in[5];
    const void* b_in     = d_in[6];
    const void* Wl1 = d_in[7];  const void* bl1 = d_in[8];
    const void* Wr1 = d_in[9];  const void* br1 = d_in[10];
    const void* We1 = d_in[11]; const void* be1 = d_in[12];
    const void* att1 = d_in[13]; const void* bo1 = d_in[14];
    const void* Wl2 = d_in[15]; const void* bl2 = d_in[16];
    const void* Wr2 = d_in[17]; const void* br2 = d_in[18];
    const void* We2 = d_in[19]; const void* be2 = d_in[20];
    const void* att2 = d_in[21]; const void* bo2 = d_in[22];
    const void* g1 = d_in[23]; const void* beta1 = d_in[24];
    const void* g2 = d_in[25]; const void* beta2 = d_in[26];
    const void* W_out = d_in[27]; const void* b_out = d_in[28];

    // workspace layout (~78 MB): flag | z fp32 | agg fp32 | den fp32 | xl bf16 | xr bf16
    int* flag  = (int*)d_ws;
    float* z   = (float*)d_ws + 64;
    float* agg = z + NN * HIDD;
    float* den = agg + NN * HIDD;
    bf16* xl   = (bf16*)(den + NN * NH);
    bf16* xr   = xl + NN * HIDD;

    k_detect<<<1, 256, 0, stream>>>((const unsigned short*)x, in_sizes[0], flag);
    k_build_z<<<NN, 128, 0, stream>>>(flag, x, node_idx, emb, W_in, b_in, z);

    // ---- layer 1 ----
    k_init<<<(NN * HIDD + 255) / 256, 256, 0, stream>>>(agg, den);
    k_proj<<<NN / 4, 128, 0, stream>>>(flag, z, Wl1, bl1, Wr1, br1, xl, xr);
    k_edge<<<NE / 2, 256, 0, stream>>>(flag, ea, ei, We1, be1, att1, xl, xr, agg, den);
    k_fin<<<NN, 128, 0, stream>>>(flag, agg, den, bo1, z, g1, beta1);

    // ---- layer 2 ----
    k_init<<<(NN * HIDD + 255) / 256, 256, 0, stream>>>(agg, den);
    k_proj<<<NN / 4, 128, 0, stream>>>(flag, z, Wl2, bl2, Wr2, br2, xl, xr);
    k_edge<<<NE / 2, 256, 0, stream>>>(flag, ea, ei, We2, be2, att2, xl, xr, agg, den);
    k_fin<<<NN, 128, 0, stream>>>(flag, agg, den, bo2, z, g2, beta2);

    k_head<<<NN, 64, 0, stream>>>(flag, z, W_out, b_out, d_out);
}

// Round 3
// 1362.518 us; speedup vs baseline: 1.8690x; 1.8690x over previous
//
#include <hip/hip_runtime.h>
#include <hip/hip_bf16.h>

#define NN 50000
#define NE 600000
#define IND 16
#define EDD 8
#define HIDD 128
#define NH 4
#define CC 32
#define EMBD 64
#define FEATD 64

typedef __hip_bfloat16 bf16;

__device__ __forceinline__ float b2f(bf16 v) { return __bfloat162float(v); }

// Load input element i from a buffer whose dtype is decided at runtime.
template <bool F32>
__device__ __forceinline__ float LD(const void* p, long long i) {
    if constexpr (F32) return ((const float*)p)[i];
    else return __bfloat162float(((const bf16*)p)[i]);
}

// ---- dtype detector, parallel version.
// fp32 data viewed as halfwords: low halves are random mantissa bits ->
// P(exp==0xFF) ~ 2^-8 -> ~128 hits in 64k halfwords. bf16 normal data: 0 hits.
__global__ void k_zero(int* __restrict__ cnt) { *cnt = 0; }

__global__ void k_detect(const unsigned short* __restrict__ x, int nhalf, int* __restrict__ cnt) {
    __shared__ int c;
    if (threadIdx.x == 0) c = 0;
    __syncthreads();
    int i = blockIdx.x * blockDim.x + threadIdx.x;
    int hits = 0;
    for (; i < nhalf; i += gridDim.x * blockDim.x)
        if ((x[i] & 0x7F80u) == 0x7F80u) hits++;
    if (hits) atomicAdd(&c, hits);
    __syncthreads();
    if (threadIdx.x == 0 && c) atomicAdd(cnt, c);
}

__device__ __forceinline__ bool is_f32(const int* cnt) { return *cnt > 8; }

// ---- z[n] = concat(relu(x[n] @ W_in + b_in), emb[node_idx[n]])
template <bool F32>
__device__ void build_z_impl(const void* x, const int* __restrict__ node_idx, const void* emb,
                             const void* W_in, const void* b_in, float* __restrict__ z) {
    int n = blockIdx.x, t = threadIdx.x;  // 128
    if (t < FEATD) {
        float acc = LD<F32>(b_in, t);
        #pragma unroll
        for (int k = 0; k < IND; k++)
            acc += LD<F32>(x, (long long)n * IND + k) * LD<F32>(W_in, k * FEATD + t);
        z[n * HIDD + t] = fmaxf(acc, 0.f);
    } else {
        int j = t - FEATD;
        z[n * HIDD + t] = LD<F32>(emb, (long long)node_idx[n] * EMBD + j);
    }
}
__global__ void k_build_z(const int* cnt, const void* x, const int* node_idx, const void* emb,
                          const void* W_in, const void* b_in, float* z) {
    if (is_f32(cnt)) build_z_impl<true>(x, node_idx, emb, W_in, b_in, z);
    else             build_z_impl<false>(x, node_idx, emb, W_in, b_in, z);
}

// ---- xl = z@Wl+bl ; xr = z@Wr+br, 4 nodes per block (weight reuse), bf16 outputs
template <bool F32>
__device__ void proj_impl(const float* __restrict__ z, const void* Wl, const void* bl,
                          const void* Wr, const void* br, bf16* __restrict__ xl,
                          bf16* __restrict__ xr) {
    __shared__ float zr[4][HIDD];
    int n0 = blockIdx.x * 4, t = threadIdx.x;  // 128
    #pragma unroll
    for (int j = 0; j < 4; j++) zr[j][t] = z[(n0 + j) * HIDD + t];
    __syncthreads();
    float al[4], ar[4];
    float blv = LD<F32>(bl, t), brv = LD<F32>(br, t);
    #pragma unroll
    for (int j = 0; j < 4; j++) { al[j] = blv; ar[j] = brv; }
    for (int k = 0; k < HIDD; k++) {
        float wl = LD<F32>(Wl, k * HIDD + t);
        float wr = LD<F32>(Wr, k * HIDD + t);
        #pragma unroll
        for (int j = 0; j < 4; j++) {
            al[j] += zr[j][k] * wl;
            ar[j] += zr[j][k] * wr;
        }
    }
    #pragma unroll
    for (int j = 0; j < 4; j++) {
        xl[(n0 + j) * HIDD + t] = __float2bfloat16(al[j]);
        xr[(n0 + j) * HIDD + t] = __float2bfloat16(ar[j]);
    }
}
__global__ void k_proj(const int* cnt, const float* z, const void* Wl, const void* bl,
                       const void* Wr, const void* br, bf16* xl, bf16* xr) {
    if (is_f32(cnt)) proj_impl<true>(z, Wl, bl, Wr, br, xl, xr);
    else             proj_impl<false>(z, Wl, bl, Wr, br, xl, xr);
}

// ---- zero agg + den
__global__ void k_init(float* __restrict__ agg, float* __restrict__ den) {
    int i = blockIdx.x * blockDim.x + threadIdx.x;
    if (i < NN * HIDD) agg[i] = 0.f;
    if (i < NN * NH) den[i] = 0.f;
}

// ---- fused edge pass: logits -> exp -> unnormalized scatter + den.
// Max-shift dropped: alpha is shift-invariant and |logit| is small here (no overflow).
template <bool F32>
__device__ void edge_impl(const void* ea, const int* __restrict__ ei, const void* We,
                          const void* be, const void* att, const bf16* __restrict__ xl,
                          const bf16* __restrict__ xr, float* __restrict__ agg,
                          float* __restrict__ den) {
    __shared__ float sWe[EDD * HIDD];
    __shared__ float sbt[2 * HIDD];  // [0:128)=be, [128:256)=att
    __shared__ float sea[2][EDD];
    int tid = threadIdx.x;  // 256 = 2 edges x 128 channels
    for (int i = tid; i < EDD * HIDD; i += 256) sWe[i] = LD<F32>(We, i);
    if (tid < HIDD) sbt[tid] = LD<F32>(be, tid);
    else            sbt[tid] = LD<F32>(att, tid - HIDD);
    int el = tid >> 7;
    int t = tid & 127;
    int e = blockIdx.x * 2 + el;  // grid = NE/2 exactly, no bounds check
    if (t < EDD) sea[el][t] = LD<F32>(ea, (long long)e * EDD + t);
    __syncthreads();
    int src = ei[e], dst = ei[NE + e];
    float ee = sbt[t];
    #pragma unroll
    for (int d = 0; d < EDD; d++) ee += sea[el][d] * sWe[d * HIDD + t];
    float xlv = b2f(xl[(long long)src * HIDD + t]);
    float s = xlv + b2f(xr[(long long)dst * HIDD + t]) + ee;
    s = (s >= 0.f) ? s : 0.2f * s;
    float ls = s * sbt[HIDD + t];
    #pragma unroll
    for (int m = 16; m; m >>= 1) ls += __shfl_xor(ls, m, 32);  // head-group reduce
    float ex = __expf(ls);
    int h = t >> 5;
    if ((t & 31) == 0) atomicAdd(&den[dst * NH + h], ex);
    atomicAdd(&agg[(long long)dst * HIDD + t], xlv * ex);
}
__global__ void k_edge(const int* cnt, const void* ea, const int* ei, const void* We,
                       const void* be, const void* att, const bf16* xl, const bf16* xr,
                       float* agg, float* den) {
    if (is_f32(cnt)) edge_impl<true>(ea, ei, We, be, att, xl, xr, agg, den);
    else             edge_impl<false>(ea, ei, We, be, att, xl, xr, agg, den);
}

// ---- h = relu(agg/den + bo); z = LN(z + h)*g + beta
template <bool F32>
__device__ void fin_impl(const float* __restrict__ agg, const float* __restrict__ den,
                         const void* bo, float* __restrict__ z, const void* g, const void* beta) {
    int n = blockIdx.x, t = threadIdx.x;  // 128
    int wave = t >> 6, lane = t & 63;
    float dn = den[n * NH + (t >> 5)];
    float a = agg[n * HIDD + t];
    float hv = (dn > 0.f) ? a / dn : 0.f;
    hv = fmaxf(hv + LD<F32>(bo, t), 0.f);
    float v = z[n * HIDD + t] + hv;
    __shared__ float part[2], part2[2];
    float s = v;
    #pragma unroll
    for (int o = 32; o; o >>= 1) s += __shfl_down(s, o);
    if (lane == 0) part[wave] = s;
    __syncthreads();
    float mu = (part[0] + part[1]) * (1.f / HIDD);
    float d = v - mu;
    float s2 = d * d;
    #pragma unroll
    for (int o = 32; o; o >>= 1) s2 += __shfl_down(s2, o);
    if (lane == 0) part2[wave] = s2;
    __syncthreads();
    float var = (part2[0] + part2[1]) * (1.f / HIDD);
    z[n * HIDD + t] = d * rsqrtf(var + 1e-5f) * LD<F32>(g, t) + LD<F32>(beta, t);
}
__global__ void k_fin(const int* cnt, const float* agg, const float* den, const void* bo,
                      float* z, const void* g, const void* beta) {
    if (is_f32(cnt)) fin_impl<true>(agg, den, bo, z, g, beta);
    else             fin_impl<false>(agg, den, bo, z, g, beta);
}

// ---- out[n] = z[n] @ W_out + b_out (one wave per node); output dtype follows flag
template <bool F32>
__device__ void head_impl(const float* __restrict__ z, const void* Wo, const void* bo, void* out) {
    int n = blockIdx.x;
    int lane = threadIdx.x;  // 64
    float acc = z[n * HIDD + lane] * LD<F32>(Wo, lane) +
                z[n * HIDD + 64 + lane] * LD<F32>(Wo, 64 + lane);
    #pragma unroll
    for (int o = 32; o; o >>= 1) acc += __shfl_down(acc, o);
    if (lane == 0) {
        float r = acc + LD<F32>(bo, 0);
        if constexpr (F32) ((float*)out)[n] = r;
        else               ((bf16*)out)[n] = __float2bfloat16(r);
    }
}
__global__ void k_head(const int* cnt, const float* z, const void* Wo, const void* bo, void* out) {
    if (is_f32(cnt)) head_impl<true>(z, Wo, bo, out);
    else             head_impl<false>(z, Wo, bo, out);
}

extern "C" void kernel_launch(void* const* d_in, const int* in_sizes, int n_in,
                              void* d_out, int out_size, void* d_ws, size_t ws_size,
                              hipStream_t stream) {
    const void* x        = d_in[0];
    const int*  node_idx = (const int*)d_in[1];
    const int*  ei       = (const int*)d_in[2];
    const void* ea       = d_in[3];
    const void* emb      = d_in[4];
    const void* W_in     = d_in[5];
    const void* b_in     = d_in[6];
    const void* Wl1 = d_in[7];  const void* bl1 = d_in[8];
    const void* Wr1 = d_in[9];  const void* br1 = d_in[10];
    const void* We1 = d_in[11]; const void* be1 = d_in[12];
    const void* att1 = d_in[13]; const void* bo1 = d_in[14];
    const void* Wl2 = d_in[15]; const void* bl2 = d_in[16];
    const void* Wr2 = d_in[17]; const void* br2 = d_in[18];
    const void* We2 = d_in[19]; const void* be2 = d_in[20];
    const void* att2 = d_in[21]; const void* bo2 = d_in[22];
    const void* g1 = d_in[23]; const void* beta1 = d_in[24];
    const void* g2 = d_in[25]; const void* beta2 = d_in[26];
    const void* W_out = d_in[27]; const void* b_out = d_in[28];

    // workspace layout (~78 MB): cnt | z fp32 | agg fp32 | den fp32 | xl bf16 | xr bf16
    int* cnt   = (int*)d_ws;
    float* z   = (float*)d_ws + 64;
    float* agg = z + NN * HIDD;
    float* den = agg + NN * HIDD;
    bf16* xl   = (bf16*)(den + NN * NH);
    bf16* xr   = xl + NN * HIDD;

    // scan only the first 64k halfwords: ~128 hits if fp32, 0 if bf16
    int nhalf = in_sizes[0] < 65536 ? in_sizes[0] : 65536;
    k_zero<<<1, 1, 0, stream>>>(cnt);
    k_detect<<<64, 256, 0, stream>>>((const unsigned short*)x, nhalf, cnt);
    k_build_z<<<NN, 128, 0, stream>>>(cnt, x, node_idx, emb, W_in, b_in, z);

    // ---- layer 1 ----
    k_init<<<(NN * HIDD + 255) / 256, 256, 0, stream>>>(agg, den);
    k_proj<<<NN / 4, 128, 0, stream>>>(cnt, z, Wl1, bl1, Wr1, br1, xl, xr);
    k_edge<<<NE / 2, 256, 0, stream>>>(cnt, ea, ei, We1, be1, att1, xl, xr, agg, den);
    k_fin<<<NN, 128, 0, stream>>>(cnt, agg, den, bo1, z, g1, beta1);

    // ---- layer 2 ----
    k_init<<<(NN * HIDD + 255) / 256, 256, 0, stream>>>(agg, den);
    k_proj<<<NN / 4, 128, 0, stream>>>(cnt, z, Wl2, bl2, Wr2, br2, xl, xr);
    k_edge<<<NE / 2, 256, 0, stream>>>(cnt, ea, ei, We2, be2, att2, xl, xr, agg, den);
    k_fin<<<NN, 128, 0, stream>>>(cnt, agg, den, bo2, z, g2, beta2);

    k_head<<<NN, 64, 0, stream>>>(cnt, z, W_out, b_out, d_out);
}